// Round 8
// baseline (80.758 us; speedup 1.0000x reference)
//
#include <hip/hip_runtime.h>
#include <cmath>

#define BB 4
#define TT 8192
#define DD 1024
#define CL 128               // timesteps per chunk (= per block)
#define DBLK 64              // d's per block (1 per lane)
#define NCH (TT/CL)          // 64 chunks per chain
#define NDB (DD/DBLK)        // 16 d-blocks
#define NCHAIN (BB*NDB)      // 64 chains
#define NBLK (NCHAIN*NCH)    // 4096 blocks
#define NPART 4              // waves per block = t-parts
#define PLEN (CL/NPART)      // 32 steps per part

typedef float fvec4 __attribute__((ext_vector_type(4)));
typedef unsigned long long u64;

// y[b,t,d] = Re(h[t]),  h[t] = r*h[t-1] + x[t],  r = exp(-|a_d|) * cis(w_d)
// Fused chunked-scan, fence-free lookback (R7), now register-resident:
//   - CL=128 -> 33 KB LDS -> 4 blocks/CU (was 2)
//   - local scan keeps h[t] in registers (fully unrolled, static indexing);
//     finish phase is y[t] = Re(h[t] + w), w *= r  -- no second LDS pass.
// All cross-block traffic RELAXED agent-scope (sc1, L3-coherent, no L2
// invalidates); payload->flag ordering via wave-local s_waitcnt vmcnt(0).

__global__ __launch_bounds__(256, 4) void fftconv_fused(
    const float* __restrict__ x, const float* __restrict__ decay,
    const float* __restrict__ freq, float2* __restrict__ agg,
    unsigned* __restrict__ flags, float* __restrict__ y)
{
    __shared__ float tile[CL*DBLK];        // 32 KB
    __shared__ float2 Ssub[NPART][DBLK];   // 2 KB  sub-part aggregates
    __shared__ float2 eoff[NPART][DBLK];   // 2 KB  exclusive in-chunk offsets
    __shared__ float2 Ebc[DBLK];           // 512 B broadcast of incoming state

    const int tid  = threadIdx.x;
    const int lane = tid & 63;
    const int part = tid >> 6;             // 0..3 (wave index = t-part)
    const int bid  = blockIdx.x;
    const int c     = bid & (NCH-1);       // chunk index (low bits: dispatch order!)
    const int chain = bid >> 6;            // NCH=64
    const int dblk  = chain & (NDB-1);
    const int b     = chain >> 4;          // NDB=16

    const int d = dblk*DBLK + lane;
    const size_t xoff = ((size_t)(b*TT + c*CL))*DD + (size_t)dblk*DBLK;

    // per-d constants
    const float a = fabsf(decay[d]);
    const float w = freq[d];
    float s, cc;
    float e = expf(-a); sincosf(w, &s, &cc);
    const float rr = e*cc, ri = e*s;                      // r
    e = expf(-a*(float)PLEN); sincosf(w*(float)PLEN, &s, &cc);
    const float Msr = e*cc, Msi = e*s;                    // r^PLEN
    e = expf(-a*(float)CL); sincosf(w*(float)CL, &s, &cc);
    const float Mr = e*cc, Mi = e*s;                      // r^CL
    e = expf(-a*(float)(PLEN*part)); sincosf(w*(float)(PLEN*part), &s, &cc);
    const float Mpr = e*cc, Mpi = e*s;                    // r^(PLEN*part)

    // ---- stage x tile into LDS (coalesced fvec4; 2-way bank alias = free) ----
    {
        const float* xb = x + xoff;
#pragma unroll
        for (int k = 0; k < 8; ++k) {
            int t  = k*16 + (tid >> 4);
            int dq = (tid & 15) << 2;
            fvec4 v = *reinterpret_cast<const fvec4*>(xb + (size_t)t*DD + dq);
            *reinterpret_cast<fvec4*>(&tile[t*DBLK + dq]) = v;
        }
    }
    __syncthreads();

    // ---- local scan from zero state; keep full h[t] history in registers ----
    float hRr[PLEN], hRi[PLEN];            // fully unrolled -> static indices
    {
        float hr = 0.f, hi = 0.f;
        const int rowbase = part*PLEN;
#pragma unroll
        for (int t = 0; t < PLEN; ++t) {
            float xv = tile[(rowbase + t)*DBLK + lane];
            float nr = fmaf(rr, hr, fmaf(-ri, hi, xv));
            hi = fmaf(rr, hi, ri*hr);
            hr = nr;
            hRr[t] = hr; hRi[t] = hi;
        }
        Ssub[part][lane] = make_float2(hr, hi);
    }
    __syncthreads();

    // ---- wave 0: stitch parts, publish aggregate + flag, then lookback ----
    if (part == 0) {
        float er = 0.f, ei = 0.f;
#pragma unroll
        for (int p = 0; p < NPART; ++p) {
            eoff[p][lane] = make_float2(er, ei);
            float2 Sp = Ssub[p][lane];
            float nr = fmaf(Msr, er, fmaf(-Msi, ei, Sp.x));
            ei = fmaf(Msr, ei, fmaf(Msi, er, Sp.y));
            er = nr;
        }
        // er,ei == chunk aggregate A (state after CL steps from zero)
        float2 Av = make_float2(er, ei);
        u64 raw; __builtin_memcpy(&raw, &Av, 8);
        __hip_atomic_store(reinterpret_cast<u64*>(&agg[(size_t)bid*DBLK + lane]),
                           raw, __ATOMIC_RELAXED, __HIP_MEMORY_SCOPE_AGENT);
        // order payload (L3) before flag (L3): drain this wave's stores only.
        asm volatile("s_waitcnt vmcnt(0)" ::: "memory");
        if (lane == 0)
            __hip_atomic_store(&flags[bid], 1u, __ATOMIC_RELAXED,
                               __HIP_MEMORY_SCOPE_AGENT);

        // ---- lookback: E = sum_{j<c} M^{c-1-j} * A_j (all sc1, no fences) ----
        const int cbase = chain*NCH;       // == bid - c

        // lane-parallel poll: lane j watches flag j (c <= 63 fits one wave).
        if (lane < c) {
            while (__hip_atomic_load(&flags[cbase + lane], __ATOMIC_RELAXED,
                                     __HIP_MEMORY_SCOPE_AGENT) == 0u) {
                __builtin_amdgcn_s_sleep(1);
            }
        }
        asm volatile("" ::: "memory");     // keep payload loads below the poll

        float Er = 0.f, Ei = 0.f;
        int j = 0;
        while (j + 8 <= c) {               // batches of 8: overlap L3 latency
            u64 q[8];
#pragma unroll
            for (int k = 0; k < 8; ++k)
                q[k] = __hip_atomic_load(
                    reinterpret_cast<u64*>(&agg[(size_t)(cbase + j + k)*DBLK + lane]),
                    __ATOMIC_RELAXED, __HIP_MEMORY_SCOPE_AGENT);
#pragma unroll
            for (int k = 0; k < 8; ++k) {
                float2 A; __builtin_memcpy(&A, &q[k], 8);
                float nr = fmaf(Mr, Er, fmaf(-Mi, Ei, A.x));
                Ei = fmaf(Mr, Ei, fmaf(Mi, Er, A.y));
                Er = nr;
            }
            j += 8;
        }
        for (; j < c; ++j) {
            u64 raw2 = __hip_atomic_load(
                reinterpret_cast<u64*>(&agg[(size_t)(cbase + j)*DBLK + lane]),
                __ATOMIC_RELAXED, __HIP_MEMORY_SCOPE_AGENT);
            float2 A; __builtin_memcpy(&A, &raw2, 8);
            float nr = fmaf(Mr, Er, fmaf(-Mi, Ei, A.x));
            Ei = fmaf(Mr, Ei, fmaf(Mi, Er, A.y));
            Er = nr;
        }
        Ebc[lane] = make_float2(Er, Ei);
    }
    __syncthreads();

    // ---- finish: S = eoff[part] + r^(PLEN*part)*E;  y[t] = Re(h[t] + r^(t+1)*S) ----
    {
        float2 Ev = Ebc[lane];
        float2 ev = eoff[part][lane];
        float Sr = ev.x + (Mpr*Ev.x - Mpi*Ev.y);
        float Si = ev.y + (Mpr*Ev.y + Mpi*Ev.x);
        float wr = rr*Sr - ri*Si;          // w = r * S
        float wi = rr*Si + ri*Sr;
        float* yp = y + xoff + (size_t)(part*PLEN)*DD + lane;
#pragma unroll
        for (int t = 0; t < PLEN; ++t) {
            __builtin_nontemporal_store(hRr[t] + wr, yp);
            yp += DD;
            float nwr = rr*wr - ri*wi;     // w *= r
            wi = rr*wi + ri*wr;
            wr = nwr;
            (void)hRi[t];
        }
    }
}

extern "C" void kernel_launch(void* const* d_in, const int* in_sizes, int n_in,
                              void* d_out, int out_size, void* d_ws, size_t ws_size,
                              hipStream_t stream) {
    const float* x     = (const float*)d_in[0];
    const float* decay = (const float*)d_in[1];
    const float* freq  = (const float*)d_in[2];
    float*       y     = (float*)d_out;

    float2*   agg   = (float2*)d_ws;                          // 4096*64*8 = 2 MB
    unsigned* flags = (unsigned*)((char*)d_ws + (size_t)NBLK*DBLK*sizeof(float2));

    // zero the lookback flags each launch (capture-legal async memset);
    // kernel-boundary implicit release flushes these zeros before the
    // kernel's sc1 reads can observe them.
    (void)hipMemsetAsync(flags, 0, NBLK*sizeof(unsigned), stream);
    fftconv_fused<<<NBLK, 256, 0, stream>>>(x, decay, freq, agg, flags, y);
}

// Round 9
// 68.431 us; speedup vs baseline: 1.1801x; 1.1801x over previous
//
#include <hip/hip_runtime.h>
#include <cmath>

#define BB 4
#define TT 8192
#define DD 1024
#define CL 256               // timesteps per chunk (= per block)
#define DBLK 32              // d's per block
#define NCH (TT/CL)          // 32 chunks per chain
#define NDB (DD/DBLK)        // 32 d-blocks
#define NCHAIN (BB*NDB)      // 128 chains
#define NBLK (NCHAIN*NCH)    // 4096 blocks
#define NPART 8              // t-parts (32 lanes each)
#define PLEN (CL/NPART)      // 32 steps per part

typedef float fvec4 __attribute__((ext_vector_type(4)));
typedef unsigned long long u64;

// y[b,t,d] = Re(h[t]),  h[t] = r*h[t-1] + x[t],  r = exp(-|a_d|) * cis(w_d)
// Fused chunked-scan, fence-free sc1 lookback (R7), with:
//   - CL=256, NCH=32  -> cheap walk  (R8 lesson: walk cost ~ NCH^2)
//   - DBLK=32 -> 32KB tile -> 4 blocks/CU (R8's occupancy win)
//   - register h-history finish: no second LDS pass (R8's win)
// All cross-block traffic RELAXED agent-scope (sc1: L2-bypassing,
// L3-coherent, no cache-maintenance ops). payload->flag ordering via
// wave-local s_waitcnt vmcnt(0).

__global__ __launch_bounds__(256, 4) void fftconv_fused(
    const float* __restrict__ x, const float* __restrict__ decay,
    const float* __restrict__ freq, float2* __restrict__ agg,
    unsigned* __restrict__ flags, float* __restrict__ y)
{
    __shared__ float tile[CL*DBLK];        // 32 KB
    __shared__ float2 Ssub[NPART][DBLK];   // 2 KB  sub-part aggregates
    __shared__ float2 eoff[NPART][DBLK];   // 2 KB  exclusive in-chunk offsets
    __shared__ float2 Ebc[DBLK];           // 256 B broadcast of incoming state

    const int tid  = threadIdx.x;
    const int l32  = tid & 31;             // d-lane within block
    const int part = tid >> 5;             // 0..7 (t-part)
    const int bid  = blockIdx.x;
    const int c     = bid & (NCH-1);       // chunk index (low bits: dispatch order!)
    const int chain = bid >> 5;            // NCH=32
    const int dblk  = chain & (NDB-1);
    const int b     = chain >> 5;          // NDB=32

    const int d = dblk*DBLK + l32;
    const size_t xoff = ((size_t)(b*TT + c*CL))*DD + (size_t)dblk*DBLK;

    // per-d constants
    const float a = fabsf(decay[d]);
    const float w = freq[d];
    float s, cc;
    float e = expf(-a); sincosf(w, &s, &cc);
    const float rr = e*cc, ri = e*s;                      // r
    e = expf(-a*(float)PLEN); sincosf(w*(float)PLEN, &s, &cc);
    const float Msr = e*cc, Msi = e*s;                    // r^PLEN
    e = expf(-a*(float)CL); sincosf(w*(float)CL, &s, &cc);
    const float Mr = e*cc, Mi = e*s;                      // r^CL
    e = expf(-a*(float)(PLEN*part)); sincosf(w*(float)(PLEN*part), &s, &cc);
    const float Mpr = e*cc, Mpi = e*s;                    // r^(PLEN*part)

    // ---- stage x tile into LDS (fvec4, 128B-contiguous per 8 lanes) ----
    {
        const float* xb = x + xoff;
#pragma unroll
        for (int k = 0; k < 8; ++k) {
            int t  = k*32 + (tid >> 3);
            int dq = (tid & 7) << 2;
            fvec4 v = *reinterpret_cast<const fvec4*>(xb + (size_t)t*DD + dq);
            *reinterpret_cast<fvec4*>(&tile[t*DBLK + dq]) = v;
        }
    }
    __syncthreads();

    // ---- local scan from zero; keep real part history in registers ----
    float hRr[PLEN];                       // fully unrolled -> static indices
    {
        float hr = 0.f, hi = 0.f;
        const int rowbase = part*PLEN;
#pragma unroll
        for (int t = 0; t < PLEN; ++t) {
            float xv = tile[(rowbase + t)*DBLK + l32];
            float nr = fmaf(rr, hr, fmaf(-ri, hi, xv));
            hi = fmaf(rr, hi, ri*hr);
            hr = nr;
            hRr[t] = hr;
        }
        Ssub[part][l32] = make_float2(hr, hi);
    }
    __syncthreads();

    // ---- tid<32: stitch parts, publish aggregate + flag, lookback walk ----
    if (tid < 32) {
        float er = 0.f, ei = 0.f;
#pragma unroll
        for (int p = 0; p < NPART; ++p) {
            eoff[p][l32] = make_float2(er, ei);
            float2 Sp = Ssub[p][l32];
            float nr = fmaf(Msr, er, fmaf(-Msi, ei, Sp.x));
            ei = fmaf(Msr, ei, fmaf(Msi, er, Sp.y));
            er = nr;
        }
        // er,ei == chunk aggregate A (state after CL steps from zero)
        float2 Av = make_float2(er, ei);
        u64 raw; __builtin_memcpy(&raw, &Av, 8);
        __hip_atomic_store(reinterpret_cast<u64*>(&agg[(size_t)bid*DBLK + l32]),
                           raw, __ATOMIC_RELAXED, __HIP_MEMORY_SCOPE_AGENT);
        // order payload (L3) before flag (L3): drain this wave's stores only.
        asm volatile("s_waitcnt vmcnt(0)" ::: "memory");
        if (l32 == 0)
            __hip_atomic_store(&flags[bid], 1u, __ATOMIC_RELAXED,
                               __HIP_MEMORY_SCOPE_AGENT);

        // ---- lookback: E = sum_{j<c} M^{c-1-j} * A_j (all sc1, no fences) ----
        const int cbase = chain*NCH;       // == bid - c

        // lane-parallel poll: lane j watches flag j (c <= 31 fits 32 lanes).
        if (l32 < c) {
            while (__hip_atomic_load(&flags[cbase + l32], __ATOMIC_RELAXED,
                                     __HIP_MEMORY_SCOPE_AGENT) == 0u) {
                __builtin_amdgcn_s_sleep(1);
            }
        }
        asm volatile("" ::: "memory");     // keep payload loads below the poll

        float Er = 0.f, Ei = 0.f;
        int j = 0;
        while (j + 8 <= c) {               // batches of 8: overlap L3 latency
            u64 q[8];
#pragma unroll
            for (int k = 0; k < 8; ++k)
                q[k] = __hip_atomic_load(
                    reinterpret_cast<u64*>(&agg[(size_t)(cbase + j + k)*DBLK + l32]),
                    __ATOMIC_RELAXED, __HIP_MEMORY_SCOPE_AGENT);
#pragma unroll
            for (int k = 0; k < 8; ++k) {
                float2 A; __builtin_memcpy(&A, &q[k], 8);
                float nr = fmaf(Mr, Er, fmaf(-Mi, Ei, A.x));
                Ei = fmaf(Mr, Ei, fmaf(Mi, Er, A.y));
                Er = nr;
            }
            j += 8;
        }
        for (; j < c; ++j) {
            u64 raw2 = __hip_atomic_load(
                reinterpret_cast<u64*>(&agg[(size_t)(cbase + j)*DBLK + l32]),
                __ATOMIC_RELAXED, __HIP_MEMORY_SCOPE_AGENT);
            float2 A; __builtin_memcpy(&A, &raw2, 8);
            float nr = fmaf(Mr, Er, fmaf(-Mi, Ei, A.x));
            Ei = fmaf(Mr, Ei, fmaf(Mi, Er, A.y));
            Er = nr;
        }
        Ebc[l32] = make_float2(Er, Ei);
    }
    __syncthreads();

    // ---- finish: S = eoff[part] + r^(PLEN*part)*E; y[t] = hRr[t] + Re(r^(t+1) S) ----
    {
        float2 Ev = Ebc[l32];
        float2 ev = eoff[part][l32];
        float Sr = ev.x + (Mpr*Ev.x - Mpi*Ev.y);
        float Si = ev.y + (Mpr*Ev.y + Mpi*Ev.x);
        float wr = rr*Sr - ri*Si;          // w = r * S
        float wi = rr*Si + ri*Sr;
        float* yp = y + xoff + (size_t)(part*PLEN)*DD + l32;
#pragma unroll
        for (int t = 0; t < PLEN; ++t) {
            __builtin_nontemporal_store(hRr[t] + wr, yp);
            yp += DD;
            float nwr = rr*wr - ri*wi;     // w *= r
            wi = rr*wi + ri*wr;
            wr = nwr;
        }
    }
}

extern "C" void kernel_launch(void* const* d_in, const int* in_sizes, int n_in,
                              void* d_out, int out_size, void* d_ws, size_t ws_size,
                              hipStream_t stream) {
    const float* x     = (const float*)d_in[0];
    const float* decay = (const float*)d_in[1];
    const float* freq  = (const float*)d_in[2];
    float*       y     = (float*)d_out;

    float2*   agg   = (float2*)d_ws;                          // 4096*32*8 = 1 MB
    unsigned* flags = (unsigned*)((char*)d_ws + (size_t)NBLK*DBLK*sizeof(float2));

    // zero the lookback flags each launch (capture-legal async memset);
    // kernel-boundary implicit release flushes these zeros before the
    // kernel's sc1 reads can observe them.
    (void)hipMemsetAsync(flags, 0, NBLK*sizeof(unsigned), stream);
    fftconv_fused<<<NBLK, 256, 0, stream>>>(x, decay, freq, agg, flags, y);
}